// Round 1
// baseline (857.968 us; speedup 1.0000x reference)
//
#include <hip/hip_runtime.h>
#include <hip/hip_bf16.h>
#include <math.h>

// Problem: B=32, N=128, S=64, D=512
// Inputs (setup_inputs order):
// 0 x[B,N] f32, 1 timesteps[B] i32, 2 fusion_feat[B,D] f32, 3 tar_image_feat[B,N,S,D] f32,
// 4 pe[5000,D] f32, 5 Wq[D,D], 6 Wk[D,D], 7 Wv[D,D], 8 Wp[D,D], 9 bp[D],
// 10 Wt1[D,D], 11 bt1[D], 12 Wt2[D,D], 13 bt2[D], 14 Wd1[2D,2D], 15 bd1[2D],
// 16 Wd2[1,2D], 17 bd2[1]
// Output: [B,N] f32, each row sorted descending.

#define BB 32
#define NN 128
#define SS 64
#define DD 512

// wave(64)-cooperative dot of two 512-f32 vectors; w is global, xl is LDS.
__device__ __forceinline__ float wave_dot512(const float* __restrict__ w,
                                             const float* __restrict__ xl, int lane) {
    const float4* w4 = reinterpret_cast<const float4*>(w);
    const float4* x4 = reinterpret_cast<const float4*>(xl);
    float4 a0 = w4[lane * 2];
    float4 a1 = w4[lane * 2 + 1];
    float4 b0 = x4[lane * 2];
    float4 b1 = x4[lane * 2 + 1];
    float s = a0.x * b0.x + a0.y * b0.y + a0.z * b0.z + a0.w * b0.w
            + a1.x * b1.x + a1.y * b1.y + a1.z * b1.z + a1.w * b1.w;
#pragma unroll
    for (int off = 32; off; off >>= 1) s += __shfl_xor(s, off);
    return s;
}

// K1: per-b: cond = MLP_t(pe[ts]); q = Wq@(fusion+cond); qk = Wk^T@q; qc = qk.cond
__global__ __launch_bounds__(256) void k1_cond(
    const int* __restrict__ ts, const float* __restrict__ pe,
    const float* __restrict__ fusion,
    const float* __restrict__ Wt1, const float* __restrict__ bt1,
    const float* __restrict__ Wt2, const float* __restrict__ bt2,
    const float* __restrict__ Wq, const float* __restrict__ Wk,
    float* __restrict__ cond, float* __restrict__ qk, float* __restrict__ qc) {
    __shared__ __align__(16) float xb[DD], hb[DD], cb[DD], qb[DD];
    __shared__ __align__(16) float qkl[4][DD];
    __shared__ float red[4];
    int b = blockIdx.x, tid = threadIdx.x, lane = tid & 63, wave = tid >> 6;
    const float* per = pe + (size_t)ts[b] * DD;
    for (int i = tid; i < DD; i += 256) xb[i] = per[i];
    __syncthreads();
    for (int j = wave; j < DD; j += 4) {
        float s = wave_dot512(Wt1 + (size_t)j * DD, xb, lane) + bt1[j];
        if (lane == 0) hb[j] = s / (1.f + expf(-s));  // silu
    }
    __syncthreads();
    for (int j = wave; j < DD; j += 4) {
        float s = wave_dot512(Wt2 + (size_t)j * DD, hb, lane) + bt2[j];
        if (lane == 0) { cb[j] = s; cond[(size_t)b * DD + j] = s; }
    }
    __syncthreads();
    for (int i = tid; i < DD; i += 256) xb[i] = fusion[(size_t)b * DD + i] + cb[i];
    __syncthreads();
    for (int j = wave; j < DD; j += 4) {
        float s = wave_dot512(Wq + (size_t)j * DD, xb, lane);
        if (lane == 0) qb[j] = s;
    }
    __syncthreads();
    // qk = Wk^T @ q : each wave accumulates over 128 rows, lane owns 8 cols
    {
        float p[8] = {0, 0, 0, 0, 0, 0, 0, 0};
        for (int j = wave * 128; j < wave * 128 + 128; ++j) {
            float qj = qb[j];
            const float4* row = reinterpret_cast<const float4*>(Wk + ((size_t)j << 9));
            float4 r0 = row[lane * 2];
            float4 r1 = row[lane * 2 + 1];
            p[0] += qj * r0.x; p[1] += qj * r0.y; p[2] += qj * r0.z; p[3] += qj * r0.w;
            p[4] += qj * r1.x; p[5] += qj * r1.y; p[6] += qj * r1.z; p[7] += qj * r1.w;
        }
#pragma unroll
        for (int e = 0; e < 8; e++) qkl[wave][lane * 8 + e] = p[e];
    }
    __syncthreads();
    float qcp = 0.f;
    for (int t = tid; t < DD; t += 256) {
        float s = qkl[0][t] + qkl[1][t] + qkl[2][t] + qkl[3][t];
        qk[(size_t)b * DD + t] = s;
        qcp += s * cb[t];
    }
#pragma unroll
    for (int off = 32; off; off >>= 1) qcp += __shfl_xor(qcp, off);
    if (lane == 0) red[wave] = qcp;
    __syncthreads();
    if (tid == 0) qc[b] = red[0] + red[1] + red[2] + red[3];
}

// K2: per (b,n): sim over S, argmax, gather best row, raw score. Streams 537MB.
__global__ __launch_bounds__(256) void k2_sim(
    const float* __restrict__ fusion, const float* __restrict__ tif,
    const float* __restrict__ x, const float* __restrict__ qk,
    const float* __restrict__ qc,
    float* __restrict__ tif_best, float* __restrict__ score) {
    __shared__ __align__(16) float fb[DD];
    __shared__ float bv_s[4];
    __shared__ int bi_s[4];
    __shared__ int bidx_s;
    __shared__ float dred[4];
    int bn = blockIdx.x, b = bn >> 7;
    int tid = threadIdx.x, lane = tid & 63, wave = tid >> 6;
    for (int i = tid; i < DD; i += 256) fb[i] = fusion[(size_t)b * DD + i];
    __syncthreads();
    const float* base = tif + (size_t)bn * SS * DD;
    float bv = -INFINITY;
    int bi = 0;
    for (int s = wave * 16; s < wave * 16 + 16; ++s) {
        float v = wave_dot512(base + (size_t)s * DD, fb, lane);
        if (v > bv) { bv = v; bi = s; }  // strict > keeps first (np.argmax)
    }
    if (lane == 0) { bv_s[wave] = bv; bi_s[wave] = bi; }
    __syncthreads();
    if (tid == 0) {
        float v = bv_s[0]; int i0 = bi_s[0];
        for (int w = 1; w < 4; w++)
            if (bv_s[w] > v) { v = bv_s[w]; i0 = bi_s[w]; }  // waves ascend in s
        bidx_s = i0;
    }
    __syncthreads();
    const float* src = base + (size_t)bidx_s * DD;
    const float* qkb = qk + (size_t)b * DD;
    float local = 0.f;
    for (int i = tid; i < DD; i += 256) {
        float vv = src[i];
        tif_best[(size_t)bn * DD + i] = vv;
        local += vv * qkb[i];
    }
#pragma unroll
    for (int off = 32; off; off >>= 1) local += __shfl_xor(local, off);
    if (lane == 0) dred[wave] = local;
    __syncthreads();
    if (tid == 0) score[bn] = dred[0] + dred[1] + dred[2] + dred[3] + qc[b] + x[bn];
}

// K3: per-b: softmax over N; vsum = sum_n w_n tif_n + cond; ve=Wv@vsum;
// new_emb=Wp@ve+bp; u = Wd1[:, :512]@new_emb + bd1  (1024-vec)
__global__ __launch_bounds__(256) void k3_attn(
    const float* __restrict__ score, const float* __restrict__ tif_best,
    const float* __restrict__ cond,
    const float* __restrict__ Wv, const float* __restrict__ Wp,
    const float* __restrict__ bp,
    const float* __restrict__ Wd1, const float* __restrict__ bd1,
    float* __restrict__ wout, float* __restrict__ u) {
    __shared__ float wl[NN];
    __shared__ __align__(16) float vsum[DD], ve[DD], ne[DD];
    __shared__ float inv_s;
    int b = blockIdx.x, tid = threadIdx.x, lane = tid & 63, wave = tid >> 6;
    if (tid < NN) wl[tid] = score[b * NN + tid];
    __syncthreads();
    if (tid == 0) {
        float m = wl[0];
        for (int i = 1; i < NN; i++) m = fmaxf(m, wl[i]);
        float ssum = 0.f;
        for (int i = 0; i < NN; i++) { float e = expf(wl[i] - m); wl[i] = e; ssum += e; }
        inv_s = 1.f / ssum;
    }
    __syncthreads();
    if (tid < NN) { wl[tid] *= inv_s; wout[b * NN + tid] = wl[tid]; }
    __syncthreads();
    for (int d = tid; d < DD; d += 256) {
        float s = 0.f;
        for (int n = 0; n < NN; n++) s += wl[n] * tif_best[((size_t)(b * NN + n)) * DD + d];
        vsum[d] = s + cond[(size_t)b * DD + d];
    }
    __syncthreads();
    for (int j = wave; j < DD; j += 4) {
        float s = wave_dot512(Wv + (size_t)j * DD, vsum, lane);
        if (lane == 0) ve[j] = s;
    }
    __syncthreads();
    for (int j = wave; j < DD; j += 4) {
        float s = wave_dot512(Wp + (size_t)j * DD, ve, lane) + bp[j];
        if (lane == 0) ne[j] = s;
    }
    __syncthreads();
    for (int r = wave; r < 2 * DD; r += 4) {
        float s = wave_dot512(Wd1 + (size_t)r * (2 * DD), ne, lane) + bd1[r];
        if (lane == 0) u[(size_t)b * (2 * DD) + r] = s;
    }
}

// K4: GEMM T[4096,512] x Wd1_b^T[512,1024] fused relu + Wd2 partial-dot.
// Block: 32 rows x 128 cols, K=512 in chunks of 32. p_part[bn][8].
__global__ __launch_bounds__(256) void k4_decode(
    const float* __restrict__ A, const float* __restrict__ Wd1,
    const float* __restrict__ Wd2, const float* __restrict__ u,
    float* __restrict__ p_part) {
    __shared__ __align__(16) float At[32][32];
    __shared__ __align__(16) float Bt[32][128];
    int rb = blockIdx.x;  // 0..127  (bn chunk of 32)
    int cb = blockIdx.y;  // 0..7    (r chunk of 128)
    int tid = threadIdx.x;
    int bn0 = rb * 32;
    int r0 = cb * 128;
    int tr = tid & 31, tn = tid >> 5;
    float acc[4][4] = {};
    for (int k0 = 0; k0 < DD; k0 += 32) {
        {
            int n = tid >> 3, kq = tid & 7;
            float4 v = *reinterpret_cast<const float4*>(&A[(size_t)(bn0 + n) * DD + k0 + kq * 4]);
            At[kq * 4 + 0][n] = v.x; At[kq * 4 + 1][n] = v.y;
            At[kq * 4 + 2][n] = v.z; At[kq * 4 + 3][n] = v.w;
        }
        for (int i = tid; i < 1024; i += 256) {
            int r = i >> 3, kq = i & 7;
            float4 v = *reinterpret_cast<const float4*>(
                &Wd1[(size_t)(r0 + r) * (2 * DD) + DD + k0 + kq * 4]);
            Bt[kq * 4 + 0][r] = v.x; Bt[kq * 4 + 1][r] = v.y;
            Bt[kq * 4 + 2][r] = v.z; Bt[kq * 4 + 3][r] = v.w;
        }
        __syncthreads();
#pragma unroll
        for (int k = 0; k < 32; k++) {
            float4 av = *reinterpret_cast<const float4*>(&At[k][tn * 4]);
            float4 bv = *reinterpret_cast<const float4*>(&Bt[k][tr * 4]);
            float a_[4] = {av.x, av.y, av.z, av.w};
            float b_[4] = {bv.x, bv.y, bv.z, bv.w};
#pragma unroll
            for (int i = 0; i < 4; i++)
#pragma unroll
                for (int j = 0; j < 4; j++) acc[i][j] += a_[i] * b_[j];
        }
        __syncthreads();
    }
    int b = bn0 >> 7;
    float pp[4] = {0, 0, 0, 0};
#pragma unroll
    for (int j = 0; j < 4; j++) {
        int r = r0 + tr * 4 + j;
        float uv = u[(size_t)b * (2 * DD) + r];
        float w2 = Wd2[r];
#pragma unroll
        for (int i = 0; i < 4; i++) {
            float h = uv + acc[i][j];
            if (h > 0.f) pp[i] += w2 * h;
        }
    }
    // reduce across tr: lanes 0..31 / 32..63 are independent tr groups
#pragma unroll
    for (int off = 16; off; off >>= 1)
#pragma unroll
        for (int i = 0; i < 4; i++) pp[i] += __shfl_xor(pp[i], off);
    if (tr == 0) {
#pragma unroll
        for (int i = 0; i < 4; i++)
            p_part[(size_t)(bn0 + tn * 4 + i) * 8 + cb] = pp[i];
    }
}

// K5: p = sum(p_part) + bd2 + w; bitonic sort 128 descending per b.
__global__ __launch_bounds__(128) void k5_sort(
    const float* __restrict__ p_part, const float* __restrict__ wout,
    const float* __restrict__ bd2, float* __restrict__ out) {
    __shared__ float v[NN];
    int b = blockIdx.x, tid = threadIdx.x;
    int bn = b * NN + tid;
    float s = bd2[0] + wout[bn];
#pragma unroll
    for (int c = 0; c < 8; c++) s += p_part[(size_t)bn * 8 + c];
    v[tid] = s;
    __syncthreads();
    for (int k = 2; k <= NN; k <<= 1) {
        for (int j = k >> 1; j > 0; j >>= 1) {
            int ixj = tid ^ j;
            if (ixj > tid) {
                float a = v[tid], bb2 = v[ixj];
                bool desc = (tid & k) == 0;
                if (desc ? (a < bb2) : (a > bb2)) { v[tid] = bb2; v[ixj] = a; }
            }
            __syncthreads();
        }
    }
    out[bn] = v[tid];
}

extern "C" void kernel_launch(void* const* d_in, const int* in_sizes, int n_in,
                              void* d_out, int out_size, void* d_ws, size_t ws_size,
                              hipStream_t stream) {
    const float* x      = (const float*)d_in[0];
    const int*   ts     = (const int*)d_in[1];
    const float* fusion = (const float*)d_in[2];
    const float* tif    = (const float*)d_in[3];
    const float* pe     = (const float*)d_in[4];
    const float* Wq     = (const float*)d_in[5];
    const float* Wk     = (const float*)d_in[6];
    const float* Wv     = (const float*)d_in[7];
    const float* Wp     = (const float*)d_in[8];
    const float* bp     = (const float*)d_in[9];
    const float* Wt1    = (const float*)d_in[10];
    const float* bt1    = (const float*)d_in[11];
    const float* Wt2    = (const float*)d_in[12];
    const float* bt2    = (const float*)d_in[13];
    const float* Wd1    = (const float*)d_in[14];
    const float* bd1    = (const float*)d_in[15];
    const float* Wd2    = (const float*)d_in[16];
    const float* bd2    = (const float*)d_in[17];

    float* ws = (float*)d_ws;
    float* cond     = ws;                // 16384
    float* qk       = ws + 16384;        // 16384
    float* qc       = ws + 32768;        // 32
    float* score    = ws + 32800;        // 4096
    float* wout     = ws + 36896;        // 4096
    float* u        = ws + 40992;        // 32768
    float* p_part   = ws + 73760;        // 32768
    float* tif_best = ws + 106528;       // 2097152  (8 MB)
    float* out = (float*)d_out;

    hipLaunchKernelGGL(k1_cond, dim3(BB), dim3(256), 0, stream,
                       ts, pe, fusion, Wt1, bt1, Wt2, bt2, Wq, Wk, cond, qk, qc);
    hipLaunchKernelGGL(k2_sim, dim3(BB * NN), dim3(256), 0, stream,
                       fusion, tif, x, qk, qc, tif_best, score);
    hipLaunchKernelGGL(k3_attn, dim3(BB), dim3(256), 0, stream,
                       score, tif_best, cond, Wv, Wp, bp, Wd1, bd1, wout, u);
    hipLaunchKernelGGL(k4_decode, dim3(128, 8), dim3(256), 0, stream,
                       tif_best, Wd1, Wd2, u, p_part);
    hipLaunchKernelGGL(k5_sort, dim3(BB), dim3(128), 0, stream,
                       p_part, wout, bd2, out);
}

// Round 2
// 250.071 us; speedup vs baseline: 3.4309x; 3.4309x over previous
//
#include <hip/hip_runtime.h>
#include <hip/hip_bf16.h>
#include <math.h>

// Problem: B=32, N=128, S=64, D=512
// Output: [B,N] f32, each row sorted descending.

#define BB 32
#define NN 128
#define SS 64
#define DD 512

// wave(64)-cooperative dot of two 512-f32 vectors; w is global, xl is LDS.
__device__ __forceinline__ float wave_dot512(const float* __restrict__ w,
                                             const float* __restrict__ xl, int lane) {
    const float4* w4 = reinterpret_cast<const float4*>(w);
    const float4* x4 = reinterpret_cast<const float4*>(xl);
    float4 a0 = w4[lane * 2];
    float4 a1 = w4[lane * 2 + 1];
    float4 b0 = x4[lane * 2];
    float4 b1 = x4[lane * 2 + 1];
    float s = a0.x * b0.x + a0.y * b0.y + a0.z * b0.z + a0.w * b0.w
            + a1.x * b1.x + a1.y * b1.y + a1.z * b1.z + a1.w * b1.w;
#pragma unroll
    for (int off = 32; off; off >>= 1) s += __shfl_xor(s, off);
    return s;
}

// Batched matvec: Y[b][j] = act(W[j][:512] . X[b] + bias[j])
// grid (R/16, B), block 256 (4 waves x 4 rows each).
// mode 0: X = Xa + b*512 ; mode 1: X = pe[ts[b]] ; mode 2: X = Xa[b] + Xb[b]
__global__ __launch_bounds__(256) void bmv(
    const float* __restrict__ W, int ldw, const float* __restrict__ bias,
    const float* __restrict__ Xa, const float* __restrict__ Xb,
    const int* __restrict__ ts, const float* __restrict__ pe,
    float* __restrict__ Y, int R, int act, int mode) {
    __shared__ __align__(16) float xl[DD];
    int b = blockIdx.y, tid = threadIdx.x, lane = tid & 63, wave = tid >> 6;
    const float* src = (mode == 1) ? (pe + (size_t)ts[b] * DD) : (Xa + (size_t)b * DD);
    if (mode == 2) {
        const float* s2 = Xb + (size_t)b * DD;
        for (int i = tid; i < DD; i += 256) xl[i] = src[i] + s2[i];
    } else {
        for (int i = tid; i < DD; i += 256) xl[i] = src[i];
    }
    __syncthreads();
    int j0 = blockIdx.x * 16 + wave * 4;
#pragma unroll
    for (int jj = 0; jj < 4; ++jj) {
        int j = j0 + jj;
        float s = wave_dot512(W + (size_t)j * ldw, xl, lane);
        if (bias) s += bias[j];
        if (act == 1) s = s / (1.f + expf(-s));  // silu
        if (lane == 0) Y[(size_t)b * R + j] = s;
    }
}

// qk[b][c] = sum_j q[b][j] * Wk[j][c]   (transposed matvec)
// grid (8, B): block covers 64 cols, 4 waves split the 512 rows.
__global__ __launch_bounds__(256) void k_qk(
    const float* __restrict__ Wk, const float* __restrict__ q,
    float* __restrict__ qk) {
    __shared__ __align__(16) float ql[DD];
    __shared__ float part[4][64];
    int b = blockIdx.y, c0 = blockIdx.x * 64;
    int tid = threadIdx.x, lane = tid & 63, wave = tid >> 6;
    for (int i = tid; i < DD; i += 256) ql[i] = q[(size_t)b * DD + i];
    __syncthreads();
    float p = 0.f;
    for (int j = wave * 128; j < wave * 128 + 128; ++j)
        p += ql[j] * Wk[(size_t)j * DD + c0 + lane];
    part[wave][lane] = p;
    __syncthreads();
    if (tid < 64)
        qk[(size_t)b * DD + c0 + tid] =
            part[0][tid] + part[1][tid] + part[2][tid] + part[3][tid];
}

// K2: per (b,n): sim over S, argmax, gather best row, raw score. Streams 537MB.
// Note: the qk.cond term is constant over n -> cancels in softmax -> dropped.
__global__ __launch_bounds__(256) void k2_sim(
    const float* __restrict__ fusion, const float* __restrict__ tif,
    const float* __restrict__ x, const float* __restrict__ qk,
    float* __restrict__ tif_best, float* __restrict__ score) {
    __shared__ __align__(16) float fb[DD];
    __shared__ float bv_s[4];
    __shared__ int bi_s[4];
    __shared__ int bidx_s;
    __shared__ float dred[4];
    int bn = blockIdx.x, b = bn >> 7;
    int tid = threadIdx.x, lane = tid & 63, wave = tid >> 6;
    for (int i = tid; i < DD; i += 256) fb[i] = fusion[(size_t)b * DD + i];
    __syncthreads();
    const float* base = tif + (size_t)bn * SS * DD;
    float bv = -INFINITY;
    int bi = 0;
    for (int s = wave * 16; s < wave * 16 + 16; ++s) {
        float v = wave_dot512(base + (size_t)s * DD, fb, lane);
        if (v > bv) { bv = v; bi = s; }  // strict > keeps first (np.argmax)
    }
    if (lane == 0) { bv_s[wave] = bv; bi_s[wave] = bi; }
    __syncthreads();
    if (tid == 0) {
        float v = bv_s[0]; int i0 = bi_s[0];
        for (int w = 1; w < 4; w++)
            if (bv_s[w] > v) { v = bv_s[w]; i0 = bi_s[w]; }  // waves ascend in s
        bidx_s = i0;
    }
    __syncthreads();
    const float* src = base + (size_t)bidx_s * DD;
    const float* qkb = qk + (size_t)b * DD;
    float local = 0.f;
    for (int i = tid; i < DD; i += 256) {
        float vv = src[i];
        tif_best[(size_t)bn * DD + i] = vv;
        local += vv * qkb[i];
    }
#pragma unroll
    for (int off = 32; off; off >>= 1) local += __shfl_xor(local, off);
    if (lane == 0) dred[wave] = local;
    __syncthreads();
    if (tid == 0) score[bn] = dred[0] + dred[1] + dred[2] + dred[3] + x[bn];
}

// softmax over N=128 per b. grid (B), block 128 (2 waves).
__global__ __launch_bounds__(128) void k_softmax(
    const float* __restrict__ score, float* __restrict__ wout) {
    __shared__ float redm[2], reds[2];
    int b = blockIdx.x, tid = threadIdx.x, lane = tid & 63, wave = tid >> 6;
    float v = score[b * NN + tid];
    float m = v;
#pragma unroll
    for (int off = 32; off; off >>= 1) m = fmaxf(m, __shfl_xor(m, off));
    if (lane == 0) redm[wave] = m;
    __syncthreads();
    m = fmaxf(redm[0], redm[1]);
    float e = expf(v - m);
    float s = e;
#pragma unroll
    for (int off = 32; off; off >>= 1) s += __shfl_xor(s, off);
    if (lane == 0) reds[wave] = s;
    __syncthreads();
    wout[b * NN + tid] = e / (reds[0] + reds[1]);
}

// vsum[b][d] = sum_n w[b][n]*tif_best[b][n][d] + cond[b][d]. grid (2, B), block 256.
__global__ __launch_bounds__(256) void k_vsum(
    const float* __restrict__ wout, const float* __restrict__ tif_best,
    const float* __restrict__ cond, float* __restrict__ vsum) {
    __shared__ float wl[NN];
    int b = blockIdx.y, d = blockIdx.x * 256 + threadIdx.x;
    if (threadIdx.x < NN) wl[threadIdx.x] = wout[b * NN + threadIdx.x];
    __syncthreads();
    const float* base = tif_best + (size_t)b * NN * DD + d;
    float s = 0.f;
#pragma unroll 8
    for (int n = 0; n < NN; n++) s += wl[n] * base[(size_t)n * DD];
    vsum[(size_t)b * DD + d] = s + cond[(size_t)b * DD + d];
}

// K4: GEMM T[4096,512] x Wd1_b^T[512,1024] fused relu + Wd2 partial-dot.
__global__ __launch_bounds__(256) void k4_decode(
    const float* __restrict__ A, const float* __restrict__ Wd1,
    const float* __restrict__ Wd2, const float* __restrict__ u,
    float* __restrict__ p_part) {
    __shared__ __align__(16) float At[32][32];
    __shared__ __align__(16) float Bt[32][128];
    int rb = blockIdx.x;  // 0..127
    int cb = blockIdx.y;  // 0..7
    int tid = threadIdx.x;
    int bn0 = rb * 32;
    int r0 = cb * 128;
    int tr = tid & 31, tn = tid >> 5;
    float acc[4][4] = {};
    for (int k0 = 0; k0 < DD; k0 += 32) {
        {
            int n = tid >> 3, kq = tid & 7;
            float4 v = *reinterpret_cast<const float4*>(&A[(size_t)(bn0 + n) * DD + k0 + kq * 4]);
            At[kq * 4 + 0][n] = v.x; At[kq * 4 + 1][n] = v.y;
            At[kq * 4 + 2][n] = v.z; At[kq * 4 + 3][n] = v.w;
        }
        for (int i = tid; i < 1024; i += 256) {
            int r = i >> 3, kq = i & 7;
            float4 v = *reinterpret_cast<const float4*>(
                &Wd1[(size_t)(r0 + r) * (2 * DD) + DD + k0 + kq * 4]);
            Bt[kq * 4 + 0][r] = v.x; Bt[kq * 4 + 1][r] = v.y;
            Bt[kq * 4 + 2][r] = v.z; Bt[kq * 4 + 3][r] = v.w;
        }
        __syncthreads();
#pragma unroll
        for (int k = 0; k < 32; k++) {
            float4 av = *reinterpret_cast<const float4*>(&At[k][tn * 4]);
            float4 bv = *reinterpret_cast<const float4*>(&Bt[k][tr * 4]);
            float a_[4] = {av.x, av.y, av.z, av.w};
            float b_[4] = {bv.x, bv.y, bv.z, bv.w};
#pragma unroll
            for (int i = 0; i < 4; i++)
#pragma unroll
                for (int j = 0; j < 4; j++) acc[i][j] += a_[i] * b_[j];
        }
        __syncthreads();
    }
    int b = bn0 >> 7;
    float pp[4] = {0, 0, 0, 0};
#pragma unroll
    for (int j = 0; j < 4; j++) {
        int r = r0 + tr * 4 + j;
        float uv = u[(size_t)b * (2 * DD) + r];
        float w2 = Wd2[r];
#pragma unroll
        for (int i = 0; i < 4; i++) {
            float h = uv + acc[i][j];
            if (h > 0.f) pp[i] += w2 * h;
        }
    }
#pragma unroll
    for (int off = 16; off; off >>= 1)
#pragma unroll
        for (int i = 0; i < 4; i++) pp[i] += __shfl_xor(pp[i], off);
    if (tr == 0) {
#pragma unroll
        for (int i = 0; i < 4; i++)
            p_part[(size_t)(bn0 + tn * 4 + i) * 8 + cb] = pp[i];
    }
}

// K5: p = sum(p_part) + bd2 + w; bitonic sort 128 descending per b.
__global__ __launch_bounds__(128) void k5_sort(
    const float* __restrict__ p_part, const float* __restrict__ wout,
    const float* __restrict__ bd2, float* __restrict__ out) {
    __shared__ float v[NN];
    int b = blockIdx.x, tid = threadIdx.x;
    int bn = b * NN + tid;
    float s = bd2[0] + wout[bn];
#pragma unroll
    for (int c = 0; c < 8; c++) s += p_part[(size_t)bn * 8 + c];
    v[tid] = s;
    __syncthreads();
    for (int k = 2; k <= NN; k <<= 1) {
        for (int j = k >> 1; j > 0; j >>= 1) {
            int ixj = tid ^ j;
            if (ixj > tid) {
                float a = v[tid], bb2 = v[ixj];
                bool desc = (tid & k) == 0;
                if (desc ? (a < bb2) : (a > bb2)) { v[tid] = bb2; v[ixj] = a; }
            }
            __syncthreads();
        }
    }
    out[bn] = v[tid];
}

extern "C" void kernel_launch(void* const* d_in, const int* in_sizes, int n_in,
                              void* d_out, int out_size, void* d_ws, size_t ws_size,
                              hipStream_t stream) {
    const float* x      = (const float*)d_in[0];
    const int*   ts     = (const int*)d_in[1];
    const float* fusion = (const float*)d_in[2];
    const float* tif    = (const float*)d_in[3];
    const float* pe     = (const float*)d_in[4];
    const float* Wq     = (const float*)d_in[5];
    const float* Wk     = (const float*)d_in[6];
    const float* Wv     = (const float*)d_in[7];
    const float* Wp     = (const float*)d_in[8];
    const float* bp     = (const float*)d_in[9];
    const float* Wt1    = (const float*)d_in[10];
    const float* bt1    = (const float*)d_in[11];
    const float* Wt2    = (const float*)d_in[12];
    const float* bt2    = (const float*)d_in[13];
    const float* Wd1    = (const float*)d_in[14];
    const float* bd1    = (const float*)d_in[15];
    const float* Wd2    = (const float*)d_in[16];
    const float* bd2    = (const float*)d_in[17];

    float* ws = (float*)d_ws;
    float* cond     = ws;                 // 16384
    float* qk       = ws + 16384;         // 16384
    float* h        = ws + 32768;         // 16384
    float* q        = ws + 49152;         // 16384
    float* score    = ws + 65536;         // 4096
    float* wout     = ws + 69632;         // 4096
    float* vsum     = ws + 73728;         // 16384
    float* ve       = ws + 90112;         // 16384
    float* ne       = ws + 106496;        // 16384
    float* u        = ws + 122880;        // 32768
    float* p_part   = ws + 155648;        // 32768
    float* tif_best = ws + 188416;        // 2097152 (8 MB)
    float* out = (float*)d_out;

    // k1: cond chain (each stage grid-parallel over rows x batch)
    hipLaunchKernelGGL(bmv, dim3(32, BB), dim3(256), 0, stream,
                       Wt1, DD, bt1, nullptr, nullptr, ts, pe, h, DD, 1, 1);
    hipLaunchKernelGGL(bmv, dim3(32, BB), dim3(256), 0, stream,
                       Wt2, DD, bt2, h, nullptr, nullptr, nullptr, cond, DD, 0, 0);
    hipLaunchKernelGGL(bmv, dim3(32, BB), dim3(256), 0, stream,
                       Wq, DD, nullptr, fusion, cond, nullptr, nullptr, q, DD, 0, 2);
    hipLaunchKernelGGL(k_qk, dim3(8, BB), dim3(256), 0, stream, Wk, q, qk);

    // k2: the 537MB streamer
    hipLaunchKernelGGL(k2_sim, dim3(BB * NN), dim3(256), 0, stream,
                       fusion, tif, x, qk, tif_best, score);

    // k3 chain
    hipLaunchKernelGGL(k_softmax, dim3(BB), dim3(128), 0, stream, score, wout);
    hipLaunchKernelGGL(k_vsum, dim3(2, BB), dim3(256), 0, stream,
                       wout, tif_best, cond, vsum);
    hipLaunchKernelGGL(bmv, dim3(32, BB), dim3(256), 0, stream,
                       Wv, DD, nullptr, vsum, nullptr, nullptr, nullptr, ve, DD, 0, 0);
    hipLaunchKernelGGL(bmv, dim3(32, BB), dim3(256), 0, stream,
                       Wp, DD, bp, ve, nullptr, nullptr, nullptr, ne, DD, 0, 0);
    hipLaunchKernelGGL(bmv, dim3(64, BB), dim3(256), 0, stream,
                       Wd1, 2 * DD, bd1, ne, nullptr, nullptr, nullptr, u, 2 * DD, 0, 0);

    // k4 + k5
    hipLaunchKernelGGL(k4_decode, dim3(128, 8), dim3(256), 0, stream,
                       tif_best, Wd1, Wd2, u, p_part);
    hipLaunchKernelGGL(k5_sort, dim3(BB), dim3(128), 0, stream,
                       p_part, wout, bd2, out);
}

// Round 3
// 193.414 us; speedup vs baseline: 4.4359x; 1.2929x over previous
//
#include <hip/hip_runtime.h>
#include <hip/hip_bf16.h>
#include <math.h>

// Problem: B=32, N=128, S=64, D=512
// Output: [B,N] f32, each row sorted descending.

#define BB 32
#define NN 128
#define SS 64
#define DD 512

typedef __attribute__((ext_vector_type(8))) short short8;
typedef __attribute__((ext_vector_type(4))) float f32x4;

__device__ __forceinline__ ushort f2bf(float f) {
    // round-to-nearest-even bf16 (inputs are normal floats)
    unsigned u = __float_as_uint(f);
    unsigned r = (u + 0x7fffu + ((u >> 16) & 1u)) >> 16;
    return (ushort)r;
}

// wave(64)-cooperative dot of two 512-f32 vectors; w is global, xl is LDS.
__device__ __forceinline__ float wave_dot512(const float* __restrict__ w,
                                             const float* __restrict__ xl, int lane) {
    const float4* w4 = reinterpret_cast<const float4*>(w);
    const float4* x4 = reinterpret_cast<const float4*>(xl);
    float4 a0 = w4[lane * 2];
    float4 a1 = w4[lane * 2 + 1];
    float4 b0 = x4[lane * 2];
    float4 b1 = x4[lane * 2 + 1];
    float s = a0.x * b0.x + a0.y * b0.y + a0.z * b0.z + a0.w * b0.w
            + a1.x * b1.x + a1.y * b1.y + a1.z * b1.z + a1.w * b1.w;
#pragma unroll
    for (int off = 32; off; off >>= 1) s += __shfl_xor(s, off);
    return s;
}

// Batched matvec: Y[b][j] = act(W[j][:512] . X[b] + bias[j])
// grid (R/16, B), block 256 (4 waves x 4 rows each).
// mode 0: X = Xa + b*512 ; mode 1: X = pe[ts[b]] ; mode 2: X = Xa[b] + Xb[b]
__global__ __launch_bounds__(256) void bmv(
    const float* __restrict__ W, int ldw, const float* __restrict__ bias,
    const float* __restrict__ Xa, const float* __restrict__ Xb,
    const int* __restrict__ ts, const float* __restrict__ pe,
    float* __restrict__ Y, int R, int act, int mode) {
    __shared__ __align__(16) float xl[DD];
    int b = blockIdx.y, tid = threadIdx.x, lane = tid & 63, wave = tid >> 6;
    const float* src = (mode == 1) ? (pe + (size_t)ts[b] * DD) : (Xa + (size_t)b * DD);
    if (mode == 2) {
        const float* s2 = Xb + (size_t)b * DD;
        for (int i = tid; i < DD; i += 256) xl[i] = src[i] + s2[i];
    } else {
        for (int i = tid; i < DD; i += 256) xl[i] = src[i];
    }
    __syncthreads();
    int j0 = blockIdx.x * 16 + wave * 4;
#pragma unroll
    for (int jj = 0; jj < 4; ++jj) {
        int j = j0 + jj;
        float s = wave_dot512(W + (size_t)j * ldw, xl, lane);
        if (bias) s += bias[j];
        if (act == 1) s = s / (1.f + expf(-s));  // silu
        if (lane == 0) Y[(size_t)b * R + j] = s;
    }
}

// qk[b][c] = sum_j q[b][j] * Wk[j][c]   (transposed matvec)
__global__ __launch_bounds__(256) void k_qk(
    const float* __restrict__ Wk, const float* __restrict__ q,
    float* __restrict__ qk) {
    __shared__ __align__(16) float ql[DD];
    __shared__ float part[4][64];
    int b = blockIdx.y, c0 = blockIdx.x * 64;
    int tid = threadIdx.x, lane = tid & 63, wave = tid >> 6;
    for (int i = tid; i < DD; i += 256) ql[i] = q[(size_t)b * DD + i];
    __syncthreads();
    float p = 0.f;
    for (int j = wave * 128; j < wave * 128 + 128; ++j)
        p += ql[j] * Wk[(size_t)j * DD + c0 + lane];
    part[wave][lane] = p;
    __syncthreads();
    if (tid < 64)
        qk[(size_t)b * DD + c0 + tid] =
            part[0][tid] + part[1][tid] + part[2][tid] + part[3][tid];
}

// Convert right half of Wd1 to bf16: Wb[r][k] = bf16(Wd1[r][512+k]).
__global__ __launch_bounds__(256) void k_convWb(
    const float* __restrict__ Wd1, ushort* __restrict__ Wb) {
    int i = blockIdx.x * 256 + threadIdx.x;  // 65536 threads, 8 elems each
    int idx = i * 8;
    int r = idx >> 9, k = idx & 511;
    const float* src = Wd1 + (size_t)r * 1024 + 512 + k;
    float4 v0 = *reinterpret_cast<const float4*>(src);
    float4 v1 = *reinterpret_cast<const float4*>(src + 4);
    ushort o[8] = {f2bf(v0.x), f2bf(v0.y), f2bf(v0.z), f2bf(v0.w),
                   f2bf(v1.x), f2bf(v1.y), f2bf(v1.z), f2bf(v1.w)};
    *reinterpret_cast<short8*>(Wb + (size_t)r * 512 + k) =
        *reinterpret_cast<short8*>(o);
}

// K2: per (b,n): sim over S, argmax, gather best row (f32 + bf16), raw score.
__global__ __launch_bounds__(256) void k2_sim(
    const float* __restrict__ fusion, const float* __restrict__ tif,
    const float* __restrict__ x, const float* __restrict__ qk,
    float* __restrict__ tif_best, ushort* __restrict__ abf,
    float* __restrict__ score) {
    __shared__ __align__(16) float fb[DD];
    __shared__ float bv_s[4];
    __shared__ int bi_s[4];
    __shared__ int bidx_s;
    __shared__ float dred[4];
    int bn = blockIdx.x, b = bn >> 7;
    int tid = threadIdx.x, lane = tid & 63, wave = tid >> 6;
    for (int i = tid; i < DD; i += 256) fb[i] = fusion[(size_t)b * DD + i];
    __syncthreads();
    const float* base = tif + (size_t)bn * SS * DD;
    float bv = -INFINITY;
    int bi = 0;
    for (int s = wave * 16; s < wave * 16 + 16; ++s) {
        float v = wave_dot512(base + (size_t)s * DD, fb, lane);
        if (v > bv) { bv = v; bi = s; }  // strict > keeps first (np.argmax)
    }
    if (lane == 0) { bv_s[wave] = bv; bi_s[wave] = bi; }
    __syncthreads();
    if (tid == 0) {
        float v = bv_s[0]; int i0 = bi_s[0];
        for (int w = 1; w < 4; w++)
            if (bv_s[w] > v) { v = bv_s[w]; i0 = bi_s[w]; }  // waves ascend in s
        bidx_s = i0;
    }
    __syncthreads();
    const float* src = base + (size_t)bidx_s * DD;
    const float* qkb = qk + (size_t)b * DD;
    float local = 0.f;
    for (int i = tid; i < DD; i += 256) {
        float vv = src[i];
        tif_best[(size_t)bn * DD + i] = vv;
        abf[(size_t)bn * DD + i] = f2bf(vv);
        local += vv * qkb[i];
    }
#pragma unroll
    for (int off = 32; off; off >>= 1) local += __shfl_xor(local, off);
    if (lane == 0) dred[wave] = local;
    __syncthreads();
    if (tid == 0) score[bn] = dred[0] + dred[1] + dred[2] + dred[3] + x[bn];
}

// vsum (softmax fused, computed redundantly per block). grid (2, B), block 256.
__global__ __launch_bounds__(256) void k_vsum(
    const float* __restrict__ score, const float* __restrict__ tif_best,
    const float* __restrict__ cond,
    float* __restrict__ wout, float* __restrict__ vsum) {
    __shared__ float wl[NN];
    __shared__ float redm[2], reds[2];
    int b = blockIdx.y, tid = threadIdx.x, lane = tid & 63, wave = tid >> 6;
    float v = 0.f;
    if (tid < NN) {
        v = score[b * NN + tid];
        float m = v;
#pragma unroll
        for (int off = 32; off; off >>= 1) m = fmaxf(m, __shfl_xor(m, off));
        if (lane == 0) redm[wave] = m;
    }
    __syncthreads();
    float m = fmaxf(redm[0], redm[1]);
    if (tid < NN) {
        float e = expf(v - m);
        wl[tid] = e;
        float s = e;
#pragma unroll
        for (int off = 32; off; off >>= 1) s += __shfl_xor(s, off);
        if (lane == 0) reds[wave] = s;
    }
    __syncthreads();
    float inv = 1.f / (reds[0] + reds[1]);
    if (blockIdx.x == 0 && tid < NN) wout[b * NN + tid] = wl[tid] * inv;
    int d = blockIdx.x * 256 + tid;
    const float* base = tif_best + (size_t)b * NN * DD + d;
    float s = 0.f;
#pragma unroll 8
    for (int n = 0; n < NN; n++) s += wl[n] * base[(size_t)n * DD];
    vsum[(size_t)b * DD + d] = s * inv + cond[(size_t)b * DD + d];
}

// K4: bf16 MFMA GEMM  C[4096,1024] = Abf[4096,512] x Wb^T, fused relu+Wd2 dot.
// Tile 128x128, BK=64, 4 waves (2x2), wave-tile 64x64 (4x4 frags of 16x16x32).
// LDS staged via global_load_lds(16B) with both-sides XOR swizzle (row&7)<<4.
__global__ __launch_bounds__(256) void k4_mfma(
    const ushort* __restrict__ Abf, const ushort* __restrict__ Wb,
    const float* __restrict__ Wd2, const float* __restrict__ u,
    float* __restrict__ p_part) {
    __shared__ ushort aS[128 * 64];  // [row][64 k] -> 128B rows, 16 KB
    __shared__ ushort bS[128 * 64];
    int tid = threadIdx.x, l = tid & 63, w = tid >> 6;
    int m0 = blockIdx.x * 128, n0 = blockIdx.y * 128;
    int wm = w >> 1, wn = w & 1;
    f32x4 acc[4][4];
#pragma unroll
    for (int i = 0; i < 4; i++)
#pragma unroll
        for (int j = 0; j < 4; j++) acc[i][j] = (f32x4){0.f, 0.f, 0.f, 0.f};

    for (int k0 = 0; k0 < DD; k0 += 64) {
#pragma unroll
        for (int i = 0; i < 4; ++i) {
            int L = i * 4096 + w * 1024 + l * 16;  // linear byte in 16KB tile
            int row = L >> 7;
            int bo = L & 127;
            int sb = bo ^ ((row & 7) << 4);  // pre-swizzled source (rule 21)
            const ushort* ga = Abf + (size_t)(m0 + row) * DD + k0 + (sb >> 1);
            const ushort* gb = Wb + (size_t)(n0 + row) * DD + k0 + (sb >> 1);
            __builtin_amdgcn_global_load_lds(
                (const __attribute__((address_space(1))) void*)ga,
                (__attribute__((address_space(3))) void*)(aS + i * 2048 + w * 512),
                16, 0, 0);
            __builtin_amdgcn_global_load_lds(
                (const __attribute__((address_space(1))) void*)gb,
                (__attribute__((address_space(3))) void*)(bS + i * 2048 + w * 512),
                16, 0, 0);
        }
        __syncthreads();
#pragma unroll
        for (int kk = 0; kk < 2; ++kk) {
            short8 af[4], bf[4];
#pragma unroll
            for (int f = 0; f < 4; ++f) {
                int ra = wm * 64 + f * 16 + (l & 15);
                int boa = (((l >> 4) * 16 + kk * 64)) ^ ((ra & 7) << 4);
                af[f] = *reinterpret_cast<const short8*>(&aS[ra * 64 + (boa >> 1)]);
                int rb = wn * 64 + f * 16 + (l & 15);
                int bob = (((l >> 4) * 16 + kk * 64)) ^ ((rb & 7) << 4);
                bf[f] = *reinterpret_cast<const short8*>(&bS[rb * 64 + (bob >> 1)]);
            }
#pragma unroll
            for (int fm = 0; fm < 4; ++fm)
#pragma unroll
                for (int fn = 0; fn < 4; ++fn)
                    acc[fm][fn] = __builtin_amdgcn_mfma_f32_16x16x32_bf16(
                        af[fm], bf[fn], acc[fm][fn], 0, 0, 0);
        }
        __syncthreads();
    }
    // epilogue: p_part[m][cb*2+wn] = sum over this block's 64 r-cols (wn half)
    int b = blockIdx.x;  // BM=128 == N rows per batch
    const float* ub = u + (size_t)b * 1024;
#pragma unroll
    for (int fm = 0; fm < 4; ++fm) {
#pragma unroll
        for (int reg = 0; reg < 4; ++reg) {
            float pp = 0.f;
#pragma unroll
            for (int fn = 0; fn < 4; ++fn) {
                int r = n0 + wn * 64 + fn * 16 + (l & 15);
                float h = acc[fm][fn][reg] + ub[r];
                if (h > 0.f) pp += Wd2[r] * h;
            }
#pragma unroll
            for (int off = 1; off < 16; off <<= 1) pp += __shfl_xor(pp, off);
            if ((l & 15) == 0) {
                int m = m0 + wm * 64 + fm * 16 + (l >> 4) * 4 + reg;
                p_part[(size_t)m * 16 + blockIdx.y * 2 + wn] = pp;
            }
        }
    }
}

// K5: p = sum(p_part) + bd2 + w; bitonic sort 128 descending per b.
__global__ __launch_bounds__(128) void k5_sort(
    const float* __restrict__ p_part, const float* __restrict__ wout,
    const float* __restrict__ bd2, float* __restrict__ out) {
    __shared__ float v[NN];
    int b = blockIdx.x, tid = threadIdx.x;
    int bn = b * NN + tid;
    float s = bd2[0] + wout[bn];
#pragma unroll
    for (int c = 0; c < 16; c++) s += p_part[(size_t)bn * 16 + c];
    v[tid] = s;
    __syncthreads();
    for (int k = 2; k <= NN; k <<= 1) {
        for (int j = k >> 1; j > 0; j >>= 1) {
            int ixj = tid ^ j;
            if (ixj > tid) {
                float a = v[tid], bb2 = v[ixj];
                bool desc = (tid & k) == 0;
                if (desc ? (a < bb2) : (a > bb2)) { v[tid] = bb2; v[ixj] = a; }
            }
            __syncthreads();
        }
    }
    out[bn] = v[tid];
}

extern "C" void kernel_launch(void* const* d_in, const int* in_sizes, int n_in,
                              void* d_out, int out_size, void* d_ws, size_t ws_size,
                              hipStream_t stream) {
    const float* x      = (const float*)d_in[0];
    const int*   ts     = (const int*)d_in[1];
    const float* fusion = (const float*)d_in[2];
    const float* tif    = (const float*)d_in[3];
    const float* pe     = (const float*)d_in[4];
    const float* Wq     = (const float*)d_in[5];
    const float* Wk     = (const float*)d_in[6];
    const float* Wv     = (const float*)d_in[7];
    const float* Wp     = (const float*)d_in[8];
    const float* bp     = (const float*)d_in[9];
    const float* Wt1    = (const float*)d_in[10];
    const float* bt1    = (const float*)d_in[11];
    const float* Wt2    = (const float*)d_in[12];
    const float* bt2    = (const float*)d_in[13];
    const float* Wd1    = (const float*)d_in[14];
    const float* bd1    = (const float*)d_in[15];
    const float* Wd2    = (const float*)d_in[16];
    const float* bd2    = (const float*)d_in[17];

    float* ws = (float*)d_ws;
    float* cond     = ws;                    // 16384
    float* qk       = cond + 16384;          // 16384
    float* h        = qk + 16384;            // 16384
    float* q        = h + 16384;             // 16384
    float* score    = q + 16384;             // 4096
    float* wout     = score + 4096;          // 4096
    float* vsum     = wout + 4096;           // 16384
    float* ve       = vsum + 16384;          // 16384
    float* ne       = ve + 16384;            // 16384
    float* u        = ne + 16384;            // 32768
    float* p_part   = u + 32768;             // 65536
    float* tif_best = p_part + 65536;        // 2097152 (8 MB)
    ushort* Abf     = (ushort*)(tif_best + 2097152);  // 2097152 ushorts (4 MB)
    ushort* Wb      = Abf + 2097152;         // 524288 ushorts (1 MB)
    float* out = (float*)d_out;

    // independent prep
    hipLaunchKernelGGL(k_convWb, dim3(256), dim3(256), 0, stream, Wd1, Wb);
    // cond chain (grid-parallel over rows x batch)
    hipLaunchKernelGGL(bmv, dim3(32, BB), dim3(256), 0, stream,
                       Wt1, DD, bt1, nullptr, nullptr, ts, pe, h, DD, 1, 1);
    hipLaunchKernelGGL(bmv, dim3(32, BB), dim3(256), 0, stream,
                       Wt2, DD, bt2, h, nullptr, nullptr, nullptr, cond, DD, 0, 0);
    hipLaunchKernelGGL(bmv, dim3(32, BB), dim3(256), 0, stream,
                       Wq, DD, nullptr, fusion, cond, nullptr, nullptr, q, DD, 0, 2);
    hipLaunchKernelGGL(k_qk, dim3(8, BB), dim3(256), 0, stream, Wk, q, qk);

    // the 537MB streamer
    hipLaunchKernelGGL(k2_sim, dim3(BB * NN), dim3(256), 0, stream,
                       fusion, tif, x, qk, tif_best, Abf, score);

    // attention chain
    hipLaunchKernelGGL(k_vsum, dim3(2, BB), dim3(256), 0, stream,
                       score, tif_best, cond, wout, vsum);
    hipLaunchKernelGGL(bmv, dim3(32, BB), dim3(256), 0, stream,
                       Wv, DD, nullptr, vsum, nullptr, nullptr, nullptr, ve, DD, 0, 0);
    hipLaunchKernelGGL(bmv, dim3(32, BB), dim3(256), 0, stream,
                       Wp, DD, bp, ve, nullptr, nullptr, nullptr, ne, DD, 0, 0);
    hipLaunchKernelGGL(bmv, dim3(64, BB), dim3(256), 0, stream,
                       Wd1, 2 * DD, bd1, ne, nullptr, nullptr, nullptr, u, 2 * DD, 0, 0);

    // decode GEMM (MFMA) + sort
    hipLaunchKernelGGL(k4_mfma, dim3(32, 8), dim3(256), 0, stream,
                       Abf, Wb, Wd2, u, p_part);
    hipLaunchKernelGGL(k5_sort, dim3(BB), dim3(128), 0, stream,
                       p_part, wout, bd2, out);
}